// Round 8
// baseline (454.498 us; speedup 1.0000x reference)
//
#include <hip/hip_runtime.h>

#define GN 8192
#define IN_DIM 512
#define ODIM 64
#define SLOPE 0.2f
#define TCOLS 128              // adj cols per tile (32 KB raw per 64-row tile)
#define NT 16                  // tiles per block (block covers 2048 cols)

typedef __attribute__((ext_vector_type(4))) float  f32x4;
typedef __attribute__((ext_vector_type(4))) int    i32x4;
typedef __attribute__((ext_vector_type(8))) short  bf16x8;
typedef __attribute__((ext_vector_type(4))) unsigned short u16x4;

typedef __attribute__((address_space(1))) const unsigned gu32;
typedef __attribute__((address_space(3))) unsigned       lu32;

static __device__ __forceinline__ float bf2f(unsigned short u) {
    return __uint_as_float(((unsigned)u) << 16);
}
static __device__ __forceinline__ unsigned short f2bf(float f) {
    union { float f; unsigned u; } c; c.f = f;
    unsigned b = c.u;
    return (unsigned short)((b + 0x7fffu + ((b >> 16) & 1u)) >> 16);  // RNE
}

// load 8 contiguous elements as bf16x8, from either wire dtype
static __device__ __forceinline__ bf16x8 load8(const void* p, size_t off, int f32) {
    if (f32) {
        f32x4 lo = *(const f32x4*)((const float*)p + off);
        f32x4 hi = *(const f32x4*)((const float*)p + off + 4);
        bf16x8 r;
        #pragma unroll
        for (int q = 0; q < 4; ++q) {
            r[q]     = (short)f2bf(lo[q]);
            r[4 + q] = (short)f2bf(hi[q]);
        }
        return r;
    }
    return *(const bf16x8*)((const ushort*)p + off);
}

// Kernel 1 (MFMA GEMM): Wh = x@W^T. Epilogue writes WhTp in B-operand-native
// layout: 16B unit U(jblk,n) holds Wh[jblk*8+0..7][n]. Also s, d, dmax, dflag.
extern "C" __global__ __launch_bounds__(256)
void gat_proj(const void* __restrict__ x_, const void* __restrict__ W_,
              const void* __restrict__ as_, const void* __restrict__ ad_,
              ushort* __restrict__ WhTp, float* __restrict__ s_arr,
              float* __restrict__ d_arr, int* __restrict__ dmax_bits,
              int* __restrict__ dflag)
{
    const int wave = threadIdx.x >> 6;
    const int lane = threadIdx.x & 63;
    unsigned xw = ((const unsigned*)x_)[lane];
    unsigned ef = (xw >> 23) & 0xffu;
    unsigned long long vt = __ballot(ef > 60u && ef < 180u);
    const int f32 = (__popcll(vt) >= 32) ? 1 : 0;
    if (blockIdx.x == 0 && threadIdx.x == 0) *dflag = f32;

    const int quad = lane >> 4;
    const int lq   = lane & 15;
    const int i0   = blockIdx.x * 64 + wave * 16;

    f32x4 acc[4] = {{0,0,0,0},{0,0,0,0},{0,0,0,0},{0,0,0,0}};
    const size_t arow = (size_t)(i0 + lq) * IN_DIM;
    #pragma unroll 2
    for (int k0 = 0; k0 < IN_DIM; k0 += 32) {
        const int kk = k0 + quad * 8;
        bf16x8 a  = load8(x_, arow + kk, f32);
        bf16x8 b0 = load8(W_, (size_t)( 0 + lq) * IN_DIM + kk, f32);
        bf16x8 b1 = load8(W_, (size_t)(16 + lq) * IN_DIM + kk, f32);
        bf16x8 b2 = load8(W_, (size_t)(32 + lq) * IN_DIM + kk, f32);
        bf16x8 b3 = load8(W_, (size_t)(48 + lq) * IN_DIM + kk, f32);
        acc[0] = __builtin_amdgcn_mfma_f32_16x16x32_bf16(a, b0, acc[0], 0, 0, 0);
        acc[1] = __builtin_amdgcn_mfma_f32_16x16x32_bf16(a, b1, acc[1], 0, 0, 0);
        acc[2] = __builtin_amdgcn_mfma_f32_16x16x32_bf16(a, b2, acc[2], 0, 0, 0);
        acc[3] = __builtin_amdgcn_mfma_f32_16x16x32_bf16(a, b3, acc[3], 0, 0, 0);
    }
    float av_s[4], av_d[4];
    #pragma unroll
    for (int t = 0; t < 4; ++t) {
        const int n = t * 16 + lq;
        av_s[t] = f32 ? ((const float*)as_)[n] : bf2f(((const ushort*)as_)[n]);
        av_d[t] = f32 ? ((const float*)ad_)[n] : bf2f(((const ushort*)ad_)[n]);
    }
    #pragma unroll
    for (int t = 0; t < 4; ++t) {
        u16x4 pk;
        #pragma unroll
        for (int r = 0; r < 4; ++r) pk[r] = f2bf(acc[t][r]);
        const size_t hw = ((size_t)((i0 >> 3) + (quad >> 1)) * 64 + t * 16 + lq) * 8
                          + (quad & 1) * 4;
        *(u16x4*)(WhTp + hw) = pk;
    }
    float ps[4], pd[4];
    #pragma unroll
    for (int r = 0; r < 4; ++r) {
        float s = 0.f, d = 0.f;
        #pragma unroll
        for (int t = 0; t < 4; ++t) {
            s = fmaf(acc[t][r], av_s[t], s);
            d = fmaf(acc[t][r], av_d[t], d);
        }
        #pragma unroll
        for (int off = 1; off < 16; off <<= 1) {
            s += __shfl_xor(s, off);
            d += __shfl_xor(d, off);
        }
        ps[r] = s; pd[r] = d;
    }
    if (lq == 0) {
        float dmx = -1e30f;
        #pragma unroll
        for (int r = 0; r < 4; ++r) {
            s_arr[i0 + quad * 4 + r] = ps[r];
            d_arr[i0 + quad * 4 + r] = pd[r];
            dmx = fmaxf(dmx, pd[r]);
        }
        if (dmx > 0.f) atomicMax(dmax_bits, __float_as_int(dmx));
    }
}

// Kernel 2: fused attention, adj streamed via global_load_lds (async DMA,
// no VGPRs, no per-load waits). 512 blocks = 128 ib x 4 jq; each block owns
// rows ib*64..+64 and cols jq*2048..+2048 as 16 tiles of 64x128 ints (32 KB),
// double-buffered in LDS. Per tile: [operand prefetch (older than DMA so its
// vmcnt wait leaves DMA in flight)] [DMA t+1] [compute t] [barrier drains
// DMA t+1, which had full compute-t cover]. Raw ints stored with XOR-unit
// swizzle: LDS unit (row r, global 16B-unit u) at u^(r&31) -> reader's
// ds_read_b128 hits the 8-words/bank minimum (conflict-free).
extern "C" __global__ __launch_bounds__(256, 2)
void gat_attn(const int* __restrict__ adj, const ushort* __restrict__ WhTp,
              const float* __restrict__ s_arr, const float* __restrict__ d_arr,
              const int* __restrict__ dmax_bits,
              float* __restrict__ accum, float* __restrict__ lsum)
{
    __shared__ int adjbuf[2][64 * TCOLS];      // 2 x 32 KB
    const int b    = blockIdx.x;               // 0..511
    const int ib   = b & 127;
    const int jq   = b >> 7;                   // 0..3
    const int wave = threadIdx.x >> 6;
    const int lane = threadIdx.x & 63;
    const int quad = lane >> 4;
    const int lq   = lane & 15;
    const int i0   = ib * 64;
    const int li   = wave * 16 + lq;           // lane's local A-row
    const int i    = i0 + li;
    const float dmax = __int_as_float(*dmax_bits);
    const float si = s_arr[i];
    const float tbv = si + dmax;
    const float mi = fmaxf(tbv, SLOPE * tbv);  // row-logit upper bound

    // DMA source geometry for this lane (fixed across tiles except column base)
    const int rloc = 2 * (wave * 8) + (lane >> 5);   // recomputed per call below
    (void)rloc;
    const int s32  = lane & 31;                       // 16B-unit slot in LDS row

    f32x4 acc0 = {0,0,0,0}, acc1 = {0,0,0,0}, acc2 = {0,0,0,0}, acc3 = {0,0,0,0};
    f32x4 acc4 = {0,0,0,0};
    bf16x8 ones;
    #pragma unroll
    for (int q = 0; q < 8; ++q) ones[q] = (short)0x3F80;

    const int jb0 = jq * (NT * TCOLS);

    // ---- prologue: DMA tile 0 into buf 0 ----
    #pragma unroll
    for (int c = 0; c < 8; ++c) {
        const int R = wave * 8 + c;                   // rowpair 0..31
        const int r = 2 * R + (lane >> 5);            // local row 0..63
        const int g = s32 ^ (r & 31);                 // swizzled global unit
        const int* gp = adj + (size_t)(i0 + r) * GN + jb0 + g * 4;
        void* lp = (char*)&adjbuf[0][0] + R * 1024;   // wave-uniform base
        __builtin_amdgcn_global_load_lds((gu32*)(const void*)gp, (lu32*)lp, 16, 0, 0);
    }
    __syncthreads();

    #pragma unroll 1
    for (int t = 0; t < NT; ++t) {
        const int jb = jb0 + t * TCOLS;
        // 1) operand prefetch for ALL 4 iters of tile t (issued before DMA:
        //    their vmcnt waits leave the younger DMA outstanding)
        f32x4 dva[4][2];
        bf16x8 bfa[4][4];
        #pragma unroll
        for (int it = 0; it < 4; ++it) {
            const int j0 = jb + it * 32 + quad * 8;
            dva[it][0] = *(const f32x4*)(d_arr + j0);
            dva[it][1] = *(const f32x4*)(d_arr + j0 + 4);
            const ushort* nb = WhTp + ((size_t)(jb >> 3) + it * 4 + quad) * 512;
            bfa[it][0] = *(const bf16x8*)(nb + ( 0 + lq) * 8);
            bfa[it][1] = *(const bf16x8*)(nb + (16 + lq) * 8);
            bfa[it][2] = *(const bf16x8*)(nb + (32 + lq) * 8);
            bfa[it][3] = *(const bf16x8*)(nb + (48 + lq) * 8);
        }
        __builtin_amdgcn_sched_barrier(0);
        // 2) DMA tile t+1 into the other buffer
        if (t < NT - 1) {
            const int jbn = jb + TCOLS;
            #pragma unroll
            for (int c = 0; c < 8; ++c) {
                const int R = wave * 8 + c;
                const int r = 2 * R + (lane >> 5);
                const int g = s32 ^ (r & 31);
                const int* gp = adj + (size_t)(i0 + r) * GN + jbn + g * 4;
                void* lp = (char*)&adjbuf[(t + 1) & 1][0] + R * 1024;
                __builtin_amdgcn_global_load_lds((gu32*)(const void*)gp, (lu32*)lp, 16, 0, 0);
            }
        }
        __builtin_amdgcn_sched_barrier(0);
        // 3) compute tile t from LDS raw ints
        const char* buf = (const char*)&adjbuf[t & 1][0];
        #pragma unroll
        for (int it = 0; it < 4; ++it) {
            const int u0 = it * 8 + 2 * quad;             // global 16B unit
            const int sw = li & 31;
            i32x4 av0 = *(const i32x4*)(buf + li * 512 + ((u0     ^ sw) * 16));
            i32x4 av1 = *(const i32x4*)(buf + li * 512 + (((u0+1) ^ sw) * 16));
            float w[8];
            #pragma unroll
            for (int q = 0; q < 4; ++q) {
                float e0 = si + dva[it][0][q];
                e0 = fmaxf(e0, SLOPE * e0);
                float v0 = __expf(e0 - mi);
                w[q] = (av0[q] > 0) ? v0 : 0.f;
                float e1 = si + dva[it][1][q];
                e1 = fmaxf(e1, SLOPE * e1);
                float v1 = __expf(e1 - mi);
                w[4 + q] = (av1[q] > 0) ? v1 : 0.f;
            }
            bf16x8 af;
            #pragma unroll
            for (int q = 0; q < 8; ++q) af[q] = (short)f2bf(w[q]);
            acc0 = __builtin_amdgcn_mfma_f32_16x16x32_bf16(af, bfa[it][0], acc0, 0, 0, 0);
            acc1 = __builtin_amdgcn_mfma_f32_16x16x32_bf16(af, bfa[it][1], acc1, 0, 0, 0);
            acc2 = __builtin_amdgcn_mfma_f32_16x16x32_bf16(af, bfa[it][2], acc2, 0, 0, 0);
            acc3 = __builtin_amdgcn_mfma_f32_16x16x32_bf16(af, bfa[it][3], acc3, 0, 0, 0);
            acc4 = __builtin_amdgcn_mfma_f32_16x16x32_bf16(af, ones, acc4, 0, 0, 0);
        }
        __syncthreads();   // drains DMA t+1 (had full compute-t cover)
    }

    // epilogue: C/D col=lq, row=quad*4+r; acc4 holds row sums in every col
    const int orow = i0 + wave * 16 + quad * 4;
    if (lq == 0) {
        #pragma unroll
        for (int r = 0; r < 4; ++r) atomicAdd(&lsum[orow + r], acc4[r]);
    }
    #pragma unroll
    for (int r = 0; r < 4; ++r) {
        atomicAdd(&accum[(size_t)(orow + r) * ODIM +  0 + lq], acc0[r]);
        atomicAdd(&accum[(size_t)(orow + r) * ODIM + 16 + lq], acc1[r]);
        atomicAdd(&accum[(size_t)(orow + r) * ODIM + 32 + lq], acc2[r]);
        atomicAdd(&accum[(size_t)(orow + r) * ODIM + 48 + lq], acc3[r]);
    }
}

// Kernel 3: out = (accum / lsum), dtype per flag
extern "C" __global__ __launch_bounds__(256)
void gat_final(const float* __restrict__ accum, const float* __restrict__ lsum,
               const int* __restrict__ flag, void* __restrict__ out)
{
    const int idx = blockIdx.x * 256 + threadIdx.x;
    const float v = accum[idx] / lsum[idx >> 6];
    if (*flag) ((float*)out)[idx] = v;
    else       ((ushort*)out)[idx] = f2bf(v);
}

extern "C" void kernel_launch(void* const* d_in, const int* in_sizes, int n_in,
                              void* d_out, int out_size, void* d_ws, size_t ws_size,
                              hipStream_t stream)
{
    const void* x     = d_in[0];
    const int*  adj   = (const int*)d_in[1];
    const void* W     = d_in[2];
    const void* a_src = d_in[3];
    const void* a_dst = d_in[4];

    char* ws = (char*)d_ws;
    size_t off = 0;
    float* accum = (float*)(ws + off);  off += (size_t)GN * ODIM * 4;      // 2 MB
    float* lsum  = (float*)(ws + off);  off += (size_t)GN * 4;             // 32 KB
    int* dmax_bits = (int*)(ws + off);  off += 128;
    size_t zero_bytes = off;                                               // zero through dmax
    int* dflag = (int*)(ws + off);      off += 128;                        // written by gat_proj
    float* s_arr = (float*)(ws + off);  off += (size_t)GN * 4;
    float* d_arr = (float*)(ws + off);  off += (size_t)GN * 4;
    ushort* WhTp = (ushort*)(ws + off); off += (size_t)ODIM * GN * 2;      // 1 MB

    hipMemsetAsync(ws, 0, zero_bytes, stream);
    gat_proj<<<GN / 64, 256, 0, stream>>>(x, W, a_src, a_dst,
                                          WhTp, s_arr, d_arr, dmax_bits, dflag);
    gat_attn<<<512, 256, 0, stream>>>(adj, WhTp, s_arr, d_arr,
                                      dmax_bits, accum, lsum);
    gat_final<<<GN * ODIM / 256, 256, 0, stream>>>(accum, lsum, dflag, d_out);
}

// Round 9
// 454.102 us; speedup vs baseline: 1.0009x; 1.0009x over previous
//
#include <hip/hip_runtime.h>

#define GN 8192
#define IN_DIM 512
#define ODIM 64
#define SLOPE 0.2f
#define TCOLS 512              // adj cols per tile
#define NT 4                   // tiles per block (block covers 2048 cols)

typedef __attribute__((ext_vector_type(4))) float  f32x4;
typedef __attribute__((ext_vector_type(4))) int    i32x4;
typedef __attribute__((ext_vector_type(8))) short  bf16x8;
typedef __attribute__((ext_vector_type(4))) unsigned short u16x4;

static __device__ __forceinline__ float bf2f(unsigned short u) {
    return __uint_as_float(((unsigned)u) << 16);
}
static __device__ __forceinline__ unsigned short f2bf(float f) {
    union { float f; unsigned u; } c; c.f = f;
    unsigned b = c.u;
    return (unsigned short)((b + 0x7fffu + ((b >> 16) & 1u)) >> 16);  // RNE
}

// load 8 contiguous elements as bf16x8, from either wire dtype
static __device__ __forceinline__ bf16x8 load8(const void* p, size_t off, int f32) {
    if (f32) {
        f32x4 lo = *(const f32x4*)((const float*)p + off);
        f32x4 hi = *(const f32x4*)((const float*)p + off + 4);
        bf16x8 r;
        #pragma unroll
        for (int q = 0; q < 4; ++q) {
            r[q]     = (short)f2bf(lo[q]);
            r[4 + q] = (short)f2bf(hi[q]);
        }
        return r;
    }
    return *(const bf16x8*)((const ushort*)p + off);
}

// Kernel 1 (MFMA GEMM): Wh = x@W^T. Epilogue writes WhTp in B-operand-native
// layout: 16B unit U(jblk,n) holds Wh[jblk*8+0..7][n]. Also s, d, dmax, dflag.
// Additionally zero-inits accum/lsum (replaces the 2MB memset; kernel boundary
// orders it before gat_attn's atomics).
extern "C" __global__ __launch_bounds__(256)
void gat_proj(const void* __restrict__ x_, const void* __restrict__ W_,
              const void* __restrict__ as_, const void* __restrict__ ad_,
              ushort* __restrict__ WhTp, float* __restrict__ s_arr,
              float* __restrict__ d_arr, int* __restrict__ dmax_bits,
              int* __restrict__ dflag, float* __restrict__ accum,
              float* __restrict__ lsum)
{
    // zero accum slice (4096 floats/block) + lsum slice (64 floats/block)
    {
        f32x4 z = {0.f, 0.f, 0.f, 0.f};
        f32x4* ap = (f32x4*)(accum + (size_t)blockIdx.x * 4096);
        #pragma unroll
        for (int k = 0; k < 4; ++k) ap[k * 256 + threadIdx.x] = z;
        if (threadIdx.x < 64) lsum[blockIdx.x * 64 + threadIdx.x] = 0.f;
    }
    const int wave = threadIdx.x >> 6;
    const int lane = threadIdx.x & 63;
    unsigned xw = ((const unsigned*)x_)[lane];
    unsigned ef = (xw >> 23) & 0xffu;
    unsigned long long vt = __ballot(ef > 60u && ef < 180u);
    const int f32 = (__popcll(vt) >= 32) ? 1 : 0;
    if (blockIdx.x == 0 && threadIdx.x == 0) *dflag = f32;

    const int quad = lane >> 4;
    const int lq   = lane & 15;
    const int i0   = blockIdx.x * 64 + wave * 16;

    f32x4 acc[4] = {{0,0,0,0},{0,0,0,0},{0,0,0,0},{0,0,0,0}};
    const size_t arow = (size_t)(i0 + lq) * IN_DIM;
    #pragma unroll 2
    for (int k0 = 0; k0 < IN_DIM; k0 += 32) {
        const int kk = k0 + quad * 8;
        bf16x8 a  = load8(x_, arow + kk, f32);
        bf16x8 b0 = load8(W_, (size_t)( 0 + lq) * IN_DIM + kk, f32);
        bf16x8 b1 = load8(W_, (size_t)(16 + lq) * IN_DIM + kk, f32);
        bf16x8 b2 = load8(W_, (size_t)(32 + lq) * IN_DIM + kk, f32);
        bf16x8 b3 = load8(W_, (size_t)(48 + lq) * IN_DIM + kk, f32);
        acc[0] = __builtin_amdgcn_mfma_f32_16x16x32_bf16(a, b0, acc[0], 0, 0, 0);
        acc[1] = __builtin_amdgcn_mfma_f32_16x16x32_bf16(a, b1, acc[1], 0, 0, 0);
        acc[2] = __builtin_amdgcn_mfma_f32_16x16x32_bf16(a, b2, acc[2], 0, 0, 0);
        acc[3] = __builtin_amdgcn_mfma_f32_16x16x32_bf16(a, b3, acc[3], 0, 0, 0);
    }
    float av_s[4], av_d[4];
    #pragma unroll
    for (int t = 0; t < 4; ++t) {
        const int n = t * 16 + lq;
        av_s[t] = f32 ? ((const float*)as_)[n] : bf2f(((const ushort*)as_)[n]);
        av_d[t] = f32 ? ((const float*)ad_)[n] : bf2f(((const ushort*)ad_)[n]);
    }
    #pragma unroll
    for (int t = 0; t < 4; ++t) {
        u16x4 pk;
        #pragma unroll
        for (int r = 0; r < 4; ++r) pk[r] = f2bf(acc[t][r]);
        const size_t hw = ((size_t)((i0 >> 3) + (quad >> 1)) * 64 + t * 16 + lq) * 8
                          + (quad & 1) * 4;
        *(u16x4*)(WhTp + hw) = pk;
    }
    float ps[4], pd[4];
    #pragma unroll
    for (int r = 0; r < 4; ++r) {
        float s = 0.f, d = 0.f;
        #pragma unroll
        for (int t = 0; t < 4; ++t) {
            s = fmaf(acc[t][r], av_s[t], s);
            d = fmaf(acc[t][r], av_d[t], d);
        }
        #pragma unroll
        for (int off = 1; off < 16; off <<= 1) {
            s += __shfl_xor(s, off);
            d += __shfl_xor(d, off);
        }
        ps[r] = s; pd[r] = d;
    }
    if (lq == 0) {
        float dmx = -1e30f;
        #pragma unroll
        for (int r = 0; r < 4; ++r) {
            s_arr[i0 + quad * 4 + r] = ps[r];
            d_arr[i0 + quad * 4 + r] = pd[r];
            dmx = fmaxf(dmx, pd[r]);
        }
        if (dmx > 0.f) atomicMax(dmax_bits, __float_as_int(dmx));
    }
}

// Kernel 2: fused attention, BARRIER-FREE wave-private pipeline.
// 512 blocks = 128 ib x 4 jq. Wave w owns global rows ib*64 + w*16 .. +16 for
// BOTH staging and compute -> LDS mask buffers are wave-private, no
// __syncthreads in the K-loop. Per tile (512 cols): 16 row-chunk loads
// (coalesced 2KB/row, 3-deep register ring, pack lag 2 into the alternate
// buffer) issued DURING compute of the current tile; waves free-run, keeping
// per-CU outstanding adj bytes high continuously (no barrier drains).
// Rolling distance-1 operand prefetch (d, b-frags) as in R6.
extern "C" __global__ __launch_bounds__(256, 2)
void gat_attn(const int* __restrict__ adj, const ushort* __restrict__ WhTp,
              const float* __restrict__ s_arr, const float* __restrict__ d_arr,
              const int* __restrict__ dmax_bits,
              float* __restrict__ accum, float* __restrict__ lsum)
{
    __shared__ unsigned char mb[4][2][16 * 68];   // [wave][buf][row*68] = 8.7 KB
    const int b    = blockIdx.x;        // 0..511
    const int ib   = b & 127;
    const int jq   = b >> 7;            // 0..3
    const int wave = threadIdx.x >> 6;
    const int lane = threadIdx.x & 63;
    const int quad = lane >> 4;
    const int lq   = lane & 15;
    const int i0   = ib * 64 + wave * 16;     // wave's global row base
    const int i    = i0 + lq;                 // lane's A-row
    const float dmax = __int_as_float(*dmax_bits);
    const float si = s_arr[i];
    const float tbv = si + dmax;
    const float mi = fmaxf(tbv, SLOPE * tbv); // row-logit upper bound
    const int jb0 = jq * (NT * TCOLS);

    unsigned char* mw = &mb[wave][0][0];      // wave-private; buf offset 1088

    i32x4 ra[3], rb[3];
    auto issue = [&](int c, int jb) {
        const int* rp = adj + (size_t)(i0 + c) * GN + jb + lane * 8;
        ra[c % 3] = *(const i32x4*)rp;
        rb[c % 3] = *(const i32x4*)(rp + 4);
    };
    auto pack = [&](int c, int buf) {
        const i32x4 va = ra[c % 3], vb = rb[c % 3];
        unsigned byte = 0;
        #pragma unroll
        for (int q = 0; q < 4; ++q) {
            byte |= (va[q] > 0 ? 1u : 0u) << q;
            byte |= (vb[q] > 0 ? 1u : 0u) << (4 + q);
        }
        mw[buf * 1088 + c * 68 + lane] = (unsigned char)byte;
    };

    f32x4 acc0 = {0,0,0,0}, acc1 = {0,0,0,0}, acc2 = {0,0,0,0}, acc3 = {0,0,0,0};
    f32x4 acc4 = {0,0,0,0};
    bf16x8 ones;
    #pragma unroll
    for (int q = 0; q < 8; ++q) ones[q] = (short)0x3F80;

    // ---- prologue: stage tile 0 -> buf 0 (ring, no barrier) ----
    #pragma unroll
    for (int c = 0; c < 16; ++c) {
        issue(c, jb0);
        if (c >= 2) pack(c - 2, 0);
    }
    pack(14, 0);
    pack(15, 0);

    // preload operands for tile 0, iter 0
    {
        const int j0 = jb0 + quad * 8;
        (void)j0;
    }
    f32x4 dv0 = *(const f32x4*)(d_arr + jb0 + quad * 8);
    f32x4 dv1 = *(const f32x4*)(d_arr + jb0 + quad * 8 + 4);
    const ushort* bb0 = WhTp + ((size_t)(jb0 >> 3) + quad) * 512;
    bf16x8 b0 = *(const bf16x8*)(bb0 + ( 0 + lq) * 8);
    bf16x8 b1 = *(const bf16x8*)(bb0 + (16 + lq) * 8);
    bf16x8 b2 = *(const bf16x8*)(bb0 + (32 + lq) * 8);
    bf16x8 b3 = *(const bf16x8*)(bb0 + (48 + lq) * 8);

    #pragma unroll 1
    for (int t = 0; t < NT; ++t) {
        const int jb   = jb0 + t * TCOLS;
        const int jbn  = jb + TCOLS;
        const bool more = (t < NT - 1);
        const int buf  = t & 1, nbuf = buf ^ 1;

        #pragma unroll
        for (int it = 0; it < 16; ++it) {
            // 1) rolling operand prefetch for next col-iter
            const int jtb = (it < 15) ? jb : (more ? jbn : jb);
            const int itn = (it < 15) ? (it + 1) : 0;
            const int jn  = jtb + itn * 32 + quad * 8;
            f32x4 ndv0 = *(const f32x4*)(d_arr + jn);
            f32x4 ndv1 = *(const f32x4*)(d_arr + jn + 4);
            const ushort* nb = WhTp + ((size_t)(jtb >> 3) + itn * 4 + quad) * 512;
            bf16x8 nb0 = *(const bf16x8*)(nb + ( 0 + lq) * 8);
            bf16x8 nb1 = *(const bf16x8*)(nb + (16 + lq) * 8);
            bf16x8 nb2 = *(const bf16x8*)(nb + (32 + lq) * 8);
            bf16x8 nb3 = *(const bf16x8*)(nb + (48 + lq) * 8);
            // 2) issue next-tile adj row-chunk (it = row index) into the ring
            if (more) issue(it, jbn);
            // 3) pack row it-2 (rows it-1, it stay in flight)
            if (more && it >= 2) pack(it - 2, nbuf);
            // 4) compute col-iter it from wave-private masks
            unsigned bw = *(const unsigned*)(mw + buf * 1088 + lq * 68 + it * 4);
            const unsigned m8 = (bw >> (quad * 8)) & 0xffu;
            float w[8];
            #pragma unroll
            for (int q = 0; q < 4; ++q) {
                float e0 = si + dv0[q];
                e0 = fmaxf(e0, SLOPE * e0);
                float v0 = __expf(e0 - mi);
                w[q] = ((m8 >> q) & 1u) ? v0 : 0.f;
                float e1 = si + dv1[q];
                e1 = fmaxf(e1, SLOPE * e1);
                float v1 = __expf(e1 - mi);
                w[4 + q] = ((m8 >> (4 + q)) & 1u) ? v1 : 0.f;
            }
            bf16x8 af;
            #pragma unroll
            for (int q = 0; q < 8; ++q) af[q] = (short)f2bf(w[q]);
            acc0 = __builtin_amdgcn_mfma_f32_16x16x32_bf16(af, b0, acc0, 0, 0, 0);
            acc1 = __builtin_amdgcn_mfma_f32_16x16x32_bf16(af, b1, acc1, 0, 0, 0);
            acc2 = __builtin_amdgcn_mfma_f32_16x16x32_bf16(af, b2, acc2, 0, 0, 0);
            acc3 = __builtin_amdgcn_mfma_f32_16x16x32_bf16(af, b3, acc3, 0, 0, 0);
            acc4 = __builtin_amdgcn_mfma_f32_16x16x32_bf16(af, ones, acc4, 0, 0, 0);
            dv0 = ndv0; dv1 = ndv1; b0 = nb0; b1 = nb1; b2 = nb2; b3 = nb3;
        }
        if (more) {
            pack(14, nbuf);
            pack(15, nbuf);
        }
    }

    // epilogue: C/D col=lq, row=quad*4+r; acc4 holds row sums in every col
    const int orow = i0 + quad * 4;
    if (lq == 0) {
        #pragma unroll
        for (int r = 0; r < 4; ++r) atomicAdd(&lsum[orow + r], acc4[r]);
    }
    #pragma unroll
    for (int r = 0; r < 4; ++r) {
        atomicAdd(&accum[(size_t)(orow + r) * ODIM +  0 + lq], acc0[r]);
        atomicAdd(&accum[(size_t)(orow + r) * ODIM + 16 + lq], acc1[r]);
        atomicAdd(&accum[(size_t)(orow + r) * ODIM + 32 + lq], acc2[r]);
        atomicAdd(&accum[(size_t)(orow + r) * ODIM + 48 + lq], acc3[r]);
    }
}

// Kernel 3: out = (accum / lsum), dtype per flag
extern "C" __global__ __launch_bounds__(256)
void gat_final(const float* __restrict__ accum, const float* __restrict__ lsum,
               const int* __restrict__ flag, void* __restrict__ out)
{
    const int idx = blockIdx.x * 256 + threadIdx.x;
    const float v = accum[idx] / lsum[idx >> 6];
    if (*flag) ((float*)out)[idx] = v;
    else       ((ushort*)out)[idx] = f2bf(v);
}

extern "C" void kernel_launch(void* const* d_in, const int* in_sizes, int n_in,
                              void* d_out, int out_size, void* d_ws, size_t ws_size,
                              hipStream_t stream)
{
    const void* x     = d_in[0];
    const int*  adj   = (const int*)d_in[1];
    const void* W     = d_in[2];
    const void* a_src = d_in[3];
    const void* a_dst = d_in[4];

    char* ws = (char*)d_ws;
    size_t off = 0;
    int* dmax_bits = (int*)(ws + off);  off += 128;
    int* dflag = (int*)(ws + off);      off += 128;
    size_t zero_bytes = off;                                               // 256 B only
    float* accum = (float*)(ws + off);  off += (size_t)GN * ODIM * 4;      // 2 MB (proj zeroes)
    float* lsum  = (float*)(ws + off);  off += (size_t)GN * 4;             // 32 KB (proj zeroes)
    float* s_arr = (float*)(ws + off);  off += (size_t)GN * 4;
    float* d_arr = (float*)(ws + off);  off += (size_t)GN * 4;
    ushort* WhTp = (ushort*)(ws + off); off += (size_t)ODIM * GN * 2;      // 1 MB

    hipMemsetAsync(ws, 0, zero_bytes, stream);
    gat_proj<<<GN / 64, 256, 0, stream>>>(x, W, a_src, a_dst,
                                          WhTp, s_arr, d_arr, dmax_bits, dflag,
                                          accum, lsum);
    gat_attn<<<512, 256, 0, stream>>>(adj, WhTp, s_arr, d_arr,
                                      dmax_bits, accum, lsum);
    gat_final<<<GN * ODIM / 256, 256, 0, stream>>>(accum, lsum, dflag, d_out);
}

// Round 10
// 426.488 us; speedup vs baseline: 1.0657x; 1.0647x over previous
//
#include <hip/hip_runtime.h>
#include <hip/hip_bf16.h>

#define GN 8192
#define IN_DIM 512
#define ODIM 64
#define SLOPE 0.2f
#define JSPLIT 16
#define JCH (GN / JSPLIT)      // 512 cols per tile
#define LSTRIDE 68             // LDS mask row stride bytes (17 words -> conflict-free)
#define NTILE 4                // tiles per block (js0 + 4t, traversed descending)

typedef __attribute__((ext_vector_type(4))) float  f32x4;
typedef __attribute__((ext_vector_type(4))) int    i32x4;
typedef __attribute__((ext_vector_type(8))) short  bf16x8;
typedef __attribute__((ext_vector_type(4))) unsigned short u16x4;

static __device__ __forceinline__ float bf2f(unsigned short u) {
    return __uint_as_float(((unsigned)u) << 16);
}
static __device__ __forceinline__ unsigned short f2bf(float f) {
    union { float f; unsigned u; } c; c.f = f;
    unsigned b = c.u;
    return (unsigned short)((b + 0x7fffu + ((b >> 16) & 1u)) >> 16);  // RNE
}

// load 8 contiguous elements as bf16x8, from either wire dtype
static __device__ __forceinline__ bf16x8 load8(const void* p, size_t off, int f32) {
    if (f32) {
        f32x4 lo = *(const f32x4*)((const float*)p + off);
        f32x4 hi = *(const f32x4*)((const float*)p + off + 4);
        bf16x8 r;
        #pragma unroll
        for (int q = 0; q < 4; ++q) {
            r[q]     = (short)f2bf(lo[q]);
            r[4 + q] = (short)f2bf(hi[q]);
        }
        return r;
    }
    return *(const bf16x8*)((const ushort*)p + off);
}

// Kernel 1 (MFMA GEMM): Wh = x@W^T. Epilogue writes WhTp in B-operand-native
// layout (16B unit U(jblk,n) = Wh[jblk*8+0..7][n]); s, d, dmax, dflag; zero-
// inits accum/lsum (kernel boundary orders it before gat_attn's atomics).
extern "C" __global__ __launch_bounds__(256)
void gat_proj(const void* __restrict__ x_, const void* __restrict__ W_,
              const void* __restrict__ as_, const void* __restrict__ ad_,
              ushort* __restrict__ WhTp, float* __restrict__ s_arr,
              float* __restrict__ d_arr, int* __restrict__ dmax_bits,
              int* __restrict__ dflag, float* __restrict__ accum,
              float* __restrict__ lsum)
{
    {
        f32x4 z = {0.f, 0.f, 0.f, 0.f};
        f32x4* ap = (f32x4*)(accum + (size_t)blockIdx.x * 4096);
        #pragma unroll
        for (int k = 0; k < 4; ++k) ap[k * 256 + threadIdx.x] = z;
        if (threadIdx.x < 64) lsum[blockIdx.x * 64 + threadIdx.x] = 0.f;
    }
    const int wave = threadIdx.x >> 6;
    const int lane = threadIdx.x & 63;
    unsigned xw = ((const unsigned*)x_)[lane];
    unsigned ef = (xw >> 23) & 0xffu;
    unsigned long long vt = __ballot(ef > 60u && ef < 180u);
    const int f32 = (__popcll(vt) >= 32) ? 1 : 0;
    if (blockIdx.x == 0 && threadIdx.x == 0) *dflag = f32;

    const int quad = lane >> 4;
    const int lq   = lane & 15;
    const int i0   = blockIdx.x * 64 + wave * 16;

    f32x4 acc[4] = {{0,0,0,0},{0,0,0,0},{0,0,0,0},{0,0,0,0}};
    const size_t arow = (size_t)(i0 + lq) * IN_DIM;
    #pragma unroll 2
    for (int k0 = 0; k0 < IN_DIM; k0 += 32) {
        const int kk = k0 + quad * 8;
        bf16x8 a  = load8(x_, arow + kk, f32);
        bf16x8 b0 = load8(W_, (size_t)( 0 + lq) * IN_DIM + kk, f32);
        bf16x8 b1 = load8(W_, (size_t)(16 + lq) * IN_DIM + kk, f32);
        bf16x8 b2 = load8(W_, (size_t)(32 + lq) * IN_DIM + kk, f32);
        bf16x8 b3 = load8(W_, (size_t)(48 + lq) * IN_DIM + kk, f32);
        acc[0] = __builtin_amdgcn_mfma_f32_16x16x32_bf16(a, b0, acc[0], 0, 0, 0);
        acc[1] = __builtin_amdgcn_mfma_f32_16x16x32_bf16(a, b1, acc[1], 0, 0, 0);
        acc[2] = __builtin_amdgcn_mfma_f32_16x16x32_bf16(a, b2, acc[2], 0, 0, 0);
        acc[3] = __builtin_amdgcn_mfma_f32_16x16x32_bf16(a, b3, acc[3], 0, 0, 0);
    }
    float av_s[4], av_d[4];
    #pragma unroll
    for (int t = 0; t < 4; ++t) {
        const int n = t * 16 + lq;
        av_s[t] = f32 ? ((const float*)as_)[n] : bf2f(((const ushort*)as_)[n]);
        av_d[t] = f32 ? ((const float*)ad_)[n] : bf2f(((const ushort*)ad_)[n]);
    }
    #pragma unroll
    for (int t = 0; t < 4; ++t) {
        u16x4 pk;
        #pragma unroll
        for (int r = 0; r < 4; ++r) pk[r] = f2bf(acc[t][r]);
        const size_t hw = ((size_t)((i0 >> 3) + (quad >> 1)) * 64 + t * 16 + lq) * 8
                          + (quad & 1) * 4;
        *(u16x4*)(WhTp + hw) = pk;
    }
    float ps[4], pd[4];
    #pragma unroll
    for (int r = 0; r < 4; ++r) {
        float s = 0.f, d = 0.f;
        #pragma unroll
        for (int t = 0; t < 4; ++t) {
            s = fmaf(acc[t][r], av_s[t], s);
            d = fmaf(acc[t][r], av_d[t], d);
        }
        #pragma unroll
        for (int off = 1; off < 16; off <<= 1) {
            s += __shfl_xor(s, off);
            d += __shfl_xor(d, off);
        }
        ps[r] = s; pd[r] = d;
    }
    if (lq == 0) {
        float dmx = -1e30f;
        #pragma unroll
        for (int r = 0; r < 4; ++r) {
            s_arr[i0 + quad * 4 + r] = ps[r];
            d_arr[i0 + quad * 4 + r] = pd[r];
            dmx = fmaxf(dmx, pd[r]);
        }
        if (dmx > 0.f) atomicMax(dmax_bits, __float_as_int(dmx));
    }
}

// Kernel 2: fused attention = R6 structure (best measured) + DEEP ring:
// pack-lag 4 / ring 5 so each adj chunk gets ~4 iter-bodies (~800+ cy) of
// latency cover (HBM miss ~900 cy, m126) instead of lag-2's ~400.
// 512 blocks = 128 ib x 4 js0; tiles js0+4t traversed DESCENDING (and ib
// reversed) to scavenge the adj tail left in L3 by the harness restore.
// Exp folded: w = expf(max(dj + k1, fma(0.2,dj,k2))), k1=si-mi, k2=0.2si-mi.
// bf16 pack via v_cvt_pk_bf16_f32 (__float22bfloat162_rn).
extern "C" __global__ __launch_bounds__(256)
void gat_attn(const int* __restrict__ adj, const ushort* __restrict__ WhTp,
              const float* __restrict__ s_arr, const float* __restrict__ d_arr,
              const int* __restrict__ dmax_bits,
              float* __restrict__ accum, float* __restrict__ lsum)
{
    __shared__ unsigned char mb[2][64 * LSTRIDE];
    const int b    = blockIdx.x;        // 0..511
    const int ib   = 127 - (b & 127);   // reversed: high rows first
    const int js0  = b >> 7;            // 0..3
    const int wave = threadIdx.x >> 6;
    const int lane = threadIdx.x & 63;
    const int quad = lane >> 4;
    const int lq   = lane & 15;
    const int i0   = ib * 64;
    const int li   = wave * 16 + lq;
    const int i    = i0 + li;
    const float dmax = __int_as_float(*dmax_bits);
    const float si = s_arr[i];
    const float tbv = si + dmax;
    const float mi = fmaxf(tbv, SLOPE * tbv);   // row-logit upper bound
    const float k1 = si - mi;                   // arg = max(dj+k1, 0.2dj+k2)
    const float k2 = SLOPE * si - mi;

    const size_t adjbase = (size_t)i0 * GN + lane * 8;

    i32x4 ra[5], rb[5];
    auto issue = [&](int c, int jb) {
        const int* rp = adj + adjbase + (size_t)(c * 4 + wave) * GN + jb;
        ra[c % 5] = ((const i32x4*)rp)[0];
        rb[c % 5] = ((const i32x4*)rp)[1];
    };
    auto pack = [&](int c, int bufsel) {
        const i32x4 va = ra[c % 5], vb = rb[c % 5];
        unsigned byte = 0;
        #pragma unroll
        for (int q = 0; q < 4; ++q) {
            byte |= (va[q] > 0 ? 1u : 0u) << q;
            byte |= (vb[q] > 0 ? 1u : 0u) << (4 + q);
        }
        mb[bufsel][(c * 4 + wave) * LSTRIDE + lane] = (unsigned char)byte;
    };

    f32x4 acc0 = {0,0,0,0}, acc1 = {0,0,0,0}, acc2 = {0,0,0,0}, acc3 = {0,0,0,0};
    f32x4 acc4 = {0,0,0,0};             // row-sum via ones-MFMA
    bf16x8 ones;
    #pragma unroll
    for (int q = 0; q < 8; ++q) ones[q] = (short)0x3F80;

    // tile t processes columns jst(t) = js0 + 4*(NTILE-1-t)  (descending)
    const int jb0 = (js0 + 4 * (NTILE - 1)) * JCH;

    // ---- prologue: stage tile 0 -> mb[0], lag-4 ring ----
    #pragma unroll
    for (int c = 0; c < 16; ++c) {
        issue(c, jb0);
        if (c >= 4) pack(c - 4, 0);
    }
    pack(12, 0); pack(13, 0); pack(14, 0); pack(15, 0);
    __syncthreads();

    // preload operands for tile 0, col-iter 0
    f32x4 dv0 = *(const f32x4*)(d_arr + jb0 + quad * 8);
    f32x4 dv1 = *(const f32x4*)(d_arr + jb0 + quad * 8 + 4);
    const ushort* bb0 = WhTp + ((size_t)(jb0 >> 3) + quad) * 512;
    bf16x8 b0 = *(const bf16x8*)(bb0 + ( 0 + lq) * 8);
    bf16x8 b1 = *(const bf16x8*)(bb0 + (16 + lq) * 8);
    bf16x8 b2 = *(const bf16x8*)(bb0 + (32 + lq) * 8);
    bf16x8 b3 = *(const bf16x8*)(bb0 + (48 + lq) * 8);

    #pragma unroll 1
    for (int t = 0; t < NTILE; ++t) {
        const int jb   = (js0 + 4 * (NTILE - 1 - t)) * JCH;
        const int jbn  = jb - 4 * JCH;          // next tile (descending)
        const bool more = (t < NTILE - 1);
        const int buf  = t & 1, nbuf = buf ^ 1;

        #pragma unroll
        for (int it = 0; it < 16; ++it) {
            // 1) rolling operand prefetch (issued before this iter's adj:
            //    its vmcnt wait never drains younger adj loads)
            const int jtb = (it < 15) ? jb : (more ? jbn : jb);
            const int itn = (it < 15) ? (it + 1) : 0;
            const int jn  = jtb + itn * 32 + quad * 8;
            f32x4 ndv0 = *(const f32x4*)(d_arr + jn);
            f32x4 ndv1 = *(const f32x4*)(d_arr + jn + 4);
            const ushort* nb = WhTp + ((size_t)(jtb >> 3) + itn * 4 + quad) * 512;
            bf16x8 nb0 = *(const bf16x8*)(nb + ( 0 + lq) * 8);
            bf16x8 nb1 = *(const bf16x8*)(nb + (16 + lq) * 8);
            bf16x8 nb2 = *(const bf16x8*)(nb + (32 + lq) * 8);
            bf16x8 nb3 = *(const bf16x8*)(nb + (48 + lq) * 8);
            // 2) issue next-tile adj chunk into the 5-deep ring
            if (more) issue(it, jbn);
            // 3) pack chunk it-4 (chunks it-3..it stay in flight: ~4 iter
            //    bodies of latency cover)
            if (more && it >= 4) pack(it - 4, nbuf);
            // 4) compute col-iter it
            unsigned bw = *(const unsigned*)(&mb[buf][li * LSTRIDE + it * 4]);
            const unsigned m8 = (bw >> (quad * 8)) & 0xffu;
            float w[8];
            #pragma unroll
            for (int q = 0; q < 4; ++q) {
                float a0 = fmaxf(dv0[q] + k1, fmaf(SLOPE, dv0[q], k2));
                float v0 = __expf(a0);
                w[q] = ((m8 >> q) & 1u) ? v0 : 0.f;
                float a1 = fmaxf(dv1[q] + k1, fmaf(SLOPE, dv1[q], k2));
                float v1 = __expf(a1);
                w[4 + q] = ((m8 >> (4 + q)) & 1u) ? v1 : 0.f;
            }
            union { bf16x8 v; __hip_bfloat162 h[4]; } af;
            #pragma unroll
            for (int q = 0; q < 4; ++q)
                af.h[q] = __float22bfloat162_rn(make_float2(w[2 * q], w[2 * q + 1]));
            acc0 = __builtin_amdgcn_mfma_f32_16x16x32_bf16(af.v, b0, acc0, 0, 0, 0);
            acc1 = __builtin_amdgcn_mfma_f32_16x16x32_bf16(af.v, b1, acc1, 0, 0, 0);
            acc2 = __builtin_amdgcn_mfma_f32_16x16x32_bf16(af.v, b2, acc2, 0, 0, 0);
            acc3 = __builtin_amdgcn_mfma_f32_16x16x32_bf16(af.v, b3, acc3, 0, 0, 0);
            acc4 = __builtin_amdgcn_mfma_f32_16x16x32_bf16(af.v, ones, acc4, 0, 0, 0);
            dv0 = ndv0; dv1 = ndv1; b0 = nb0; b1 = nb1; b2 = nb2; b3 = nb3;
        }
        if (more) {
            pack(12, nbuf); pack(13, nbuf); pack(14, nbuf); pack(15, nbuf);
        }
        __syncthreads();
    }

    // epilogue: C/D col=lq, row=quad*4+r; acc4 holds row sums in every col
    const int orow = i0 + wave * 16 + quad * 4;
    if (lq == 0) {
        #pragma unroll
        for (int r = 0; r < 4; ++r) atomicAdd(&lsum[orow + r], acc4[r]);
    }
    #pragma unroll
    for (int r = 0; r < 4; ++r) {
        atomicAdd(&accum[(size_t)(orow + r) * ODIM +  0 + lq], acc0[r]);
        atomicAdd(&accum[(size_t)(orow + r) * ODIM + 16 + lq], acc1[r]);
        atomicAdd(&accum[(size_t)(orow + r) * ODIM + 32 + lq], acc2[r]);
        atomicAdd(&accum[(size_t)(orow + r) * ODIM + 48 + lq], acc3[r]);
    }
}

// Kernel 3: out = (accum / lsum), dtype per flag
extern "C" __global__ __launch_bounds__(256)
void gat_final(const float* __restrict__ accum, const float* __restrict__ lsum,
               const int* __restrict__ flag, void* __restrict__ out)
{
    const int idx = blockIdx.x * 256 + threadIdx.x;
    const float v = accum[idx] / lsum[idx >> 6];
    if (*flag) ((float*)out)[idx] = v;
    else       ((ushort*)out)[idx] = f2bf(v);
}

extern "C" void kernel_launch(void* const* d_in, const int* in_sizes, int n_in,
                              void* d_out, int out_size, void* d_ws, size_t ws_size,
                              hipStream_t stream)
{
    const void* x     = d_in[0];
    const int*  adj   = (const int*)d_in[1];
    const void* W     = d_in[2];
    const void* a_src = d_in[3];
    const void* a_dst = d_in[4];

    char* ws = (char*)d_ws;
    size_t off = 0;
    int* dmax_bits = (int*)(ws + off);  off += 128;
    int* dflag = (int*)(ws + off);      off += 128;
    size_t zero_bytes = off;                                               // 256 B only
    float* accum = (float*)(ws + off);  off += (size_t)GN * ODIM * 4;      // 2 MB (proj zeroes)
    float* lsum  = (float*)(ws + off);  off += (size_t)GN * 4;             // 32 KB (proj zeroes)
    float* s_arr = (float*)(ws + off);  off += (size_t)GN * 4;
    float* d_arr = (float*)(ws + off);  off += (size_t)GN * 4;
    ushort* WhTp = (ushort*)(ws + off); off += (size_t)ODIM * GN * 2;      // 1 MB

    hipMemsetAsync(ws, 0, zero_bytes, stream);
    gat_proj<<<GN / 64, 256, 0, stream>>>(x, W, a_src, a_dst,
                                          WhTp, s_arr, d_arr, dmax_bits, dflag,
                                          accum, lsum);
    gat_attn<<<512, 256, 0, stream>>>(adj, WhTp, s_arr, d_arr,
                                      dmax_bits, accum, lsum);
    gat_final<<<GN * ODIM / 256, 256, 0, stream>>>(accum, lsum, dflag, d_out);
}